// Round 12
// baseline (452.557 us; speedup 1.0000x reference)
//
#include <hip/hip_runtime.h>
#include <cstdint>

typedef __attribute__((ext_vector_type(8))) _Float16 half8;   // 8 fp16 = 4 VGPRs
typedef __attribute__((ext_vector_type(16))) float   f32x16;  // 32x32 MFMA acc

#define BN 2
#define NN 16384
#define FH 64
#define FW 64
#define GH 256
#define GW 256
#define CC 128
#define M_TOTAL (4*BN*NN)    // 131072
#define MROWS 64
#define NBLK (M_TOTAL/MROWS) // 2048

// LDS strides (fp16 elems)
#define SX  456              // X [64][448+pad]
#define SHC 520              // Hc (H1 512-col chunk) [64][512+pad]
#define S2H 520              // H2 [64][512+pad]
#define S3  264              // H3 [64][256+pad]
#define S4  136              // H4 [64][128+pad]
#define OFF_HC 29184         // 64*SX ; Hc spans [29184, 62464)
#define OFF_H3 62464         // virgin region after Hc ; H3 spans [62464, 79360)
#define LDS_ELEMS 79360      // 158720 B <= 160 KiB -> 1 block/CU

#define MFMA(a,b,c) __builtin_amdgcn_mfma_f32_32x32x16_f16((a),(b),(c),0,0,0)

static __device__ __forceinline__ f32x16 zero16() {
  f32x16 z;
#pragma unroll
  for (int i = 0; i < 16; ++i) z[i] = 0.f;
  return z;
}
static __device__ __forceinline__ half8 zero8() {
  half8 z;
#pragma unroll
  for (int e = 0; e < 8; ++e) z[e] = (_Float16)0.f;
  return z;
}

// ---- staging loads (batch NB kt) ----
// Asymmetric pipeline: A (L2-latency ~200-300cyc) runs 3-deep, B (LDS) 2-deep.
// Arch budget ~128: A-staging 48 + B-staging 32 + addr/temps ~30 fits; acc in AGPR.
template<int NB>
static __device__ __forceinline__ void ldA2(half8 (&A0)[NB], half8 (&A1)[NB],
    const _Float16* wa, const _Float16* wb, int t) {
#pragma unroll
  for (int i = 0; i < NB; ++i) {
    const int kt = t * NB + i;
    A0[i] = *(const half8*)(wa + kt * 512);
    A1[i] = *(const half8*)(wb + kt * 512);
  }
}
template<int NB>
static __device__ __forceinline__ void ldA1(half8 (&A)[NB], const _Float16* wa, int t) {
#pragma unroll
  for (int i = 0; i < NB; ++i) A[i] = *(const half8*)(wa + (t * NB + i) * 512);
}
template<int NB>
static __device__ __forceinline__ void ldB2(half8 (&B0)[NB], half8 (&B1)[NB],
    const _Float16* p0, const _Float16* p1, int t) {
#pragma unroll
  for (int i = 0; i < NB; ++i) {
    const int kt = t * NB + i;
    B0[i] = *(const half8*)(p0 + kt * 16);
    B1[i] = *(const half8*)(p1 + kt * 16);
  }
}
template<int NB>
static __device__ __forceinline__ void ldB1(half8 (&B)[NB], const _Float16* p, int t) {
#pragma unroll
  for (int i = 0; i < NB; ++i) B[i] = *(const half8*)(p + (t * NB + i) * 16);
}

// ---- pinned MFMA bursts ----
template<int NB>
static __device__ __forceinline__ void mm_22(f32x16& a00, f32x16& a01, f32x16& a10, f32x16& a11,
    const half8 (&A0)[NB], const half8 (&A1)[NB], const half8 (&B0)[NB], const half8 (&B1)[NB]) {
  __builtin_amdgcn_sched_barrier(0);
  __builtin_amdgcn_s_setprio(1);
#pragma unroll
  for (int i = 0; i < NB; ++i) {
    a00 = MFMA(A0[i], B0[i], a00);
    a01 = MFMA(A0[i], B1[i], a01);
    a10 = MFMA(A1[i], B0[i], a10);
    a11 = MFMA(A1[i], B1[i], a11);
  }
  __builtin_amdgcn_s_setprio(0);
  __builtin_amdgcn_sched_barrier(0);
}
template<int NB>
static __device__ __forceinline__ void mm_12(f32x16& lo, f32x16& hi,
    const half8 (&A)[NB], const half8 (&B0)[NB], const half8 (&B1)[NB]) {
  __builtin_amdgcn_sched_barrier(0);
  __builtin_amdgcn_s_setprio(1);
#pragma unroll
  for (int i = 0; i < NB; ++i) {
    lo = MFMA(A[i], B0[i], lo);
    hi = MFMA(A[i], B1[i], hi);
  }
  __builtin_amdgcn_s_setprio(0);
  __builtin_amdgcn_sched_barrier(0);
}
template<int NB>
static __device__ __forceinline__ void mm_11(f32x16& acc,
    const half8 (&A)[NB], const half8 (&B)[NB]) {
  __builtin_amdgcn_sched_barrier(0);
  __builtin_amdgcn_s_setprio(1);
#pragma unroll
  for (int i = 0; i < NB; ++i) acc = MFMA(A[i], B[i], acc);
  __builtin_amdgcn_s_setprio(0);
  __builtin_amdgcn_sched_barrier(0);
}

// ---------- weight fp32 -> packed fp16 32x16 MFMA A-fragment tiles ----------
__global__ void pack_w(const float* __restrict__ wsrc, _Float16* __restrict__ out,
                       int NT, int K, int KT) {   // NT = NOUT/32
  int idx = blockIdx.x * 256 + threadIdx.x;
  int total = NT * KT * 64;
  if (idx >= total) return;
  int l = idx & 63;
  int t = idx >> 6;
  int kt = t % KT;
  int jt = t / KT;
  int row = jt * 32 + (l & 31);
  int k0 = kt * 16 + (l >> 5) * 8;
  _Float16* o = out + (size_t)idx * 8;
#pragma unroll
  for (int e = 0; e < 8; ++e) {
    int k = k0 + e;
    float v = (k < K) ? wsrc[(size_t)row * K + k] : 0.f;
    o[e] = (_Float16)v;
  }
}

// ---------- CHW -> HWC fp16 transpose ----------
__global__ void transpose_to_hwc(const float* __restrict__ in, _Float16* __restrict__ out,
                                 int C, int HH, int WW) {
  __shared__ float tile[32][33];
  const int xt = blockIdx.x, ct = blockIdx.y;
  const int bb = blockIdx.z / HH, y = blockIdx.z % HH;
  const int tx = threadIdx.x, ty = threadIdx.y;
  const int x0 = xt * 32, c0 = ct * 32;
#pragma unroll
  for (int i = 0; i < 4; ++i) {
    int c = c0 + ty + i * 8;
    tile[ty + i * 8][tx] = in[((size_t)(bb * C + c) * HH + y) * WW + x0 + tx];
  }
  __syncthreads();
#pragma unroll
  for (int i = 0; i < 4; ++i) {
    int x = x0 + ty + i * 8;
    out[((size_t)(bb * HH + y) * WW + x) * C + c0 + tx] = (_Float16)tile[tx][ty + i * 8];
  }
}

// ---------- store one 32x32 D-tile to LDS, bias+relu, 8B-vectorized ----------
// D layout (A=W, B=acts): act-row m = lane&31, out-ch n = (reg&3)+8*(reg>>2)+4*(lane>>5)
template<bool RELU>
static __device__ __forceinline__ void store_tile(const f32x16 acc, _Float16* lout, int ldo,
                                                  int row0, int col0,
                                                  const float* __restrict__ biasBase, int lane) {
  const int m = row0 + (lane & 31);
  const int s4 = (lane >> 5) * 4;
  _Float16* rp = lout + (size_t)m * ldo + col0 + s4;
  const float* bp = biasBase + s4;
#pragma unroll
  for (int g = 0; g < 4; ++g) {
    float4 bv = *(const float4*)(bp + 8 * g);
    union { _Float16 h[4]; unsigned long long u; } pk;
#pragma unroll
    for (int e = 0; e < 4; ++e) {
      float v = acc[4 * g + e] + ((const float*)&bv)[e];
      if (RELU) v = fmaxf(v, 0.f);
      pk.h[e] = (_Float16)v;
    }
    *(unsigned long long*)(rp + 8 * g) = pk.u;
  }
}

// 6-step rolling schedule macros (period lcm(3,2)=6): A 3-deep {s,t,u}, B 2-deep {p,q}.
// mm(u) consumes A-set u%3, B-set u%2; loads issue A(u+2), B(u+1).
#define ROLL6_22(b6, LDBP0, LDBP1) \
  ldA2<2>(uA0,uA1, wa,wb,(b6)+2); ldB2<2>(qB0,qB1, LDBP0,LDBP1,(b6)+1); mm_22<2>(aR0,aR1,aR2,aR3, sA0,sA1,pB0,pB1); \
  ldA2<2>(sA0,sA1, wa,wb,(b6)+3); ldB2<2>(pB0,pB1, LDBP0,LDBP1,(b6)+2); mm_22<2>(aR0,aR1,aR2,aR3, tA0,tA1,qB0,qB1); \
  ldA2<2>(tA0,tA1, wa,wb,(b6)+4); ldB2<2>(qB0,qB1, LDBP0,LDBP1,(b6)+3); mm_22<2>(aR0,aR1,aR2,aR3, uA0,uA1,pB0,pB1); \
  ldA2<2>(uA0,uA1, wa,wb,(b6)+5); ldB2<2>(pB0,pB1, LDBP0,LDBP1,(b6)+4); mm_22<2>(aR0,aR1,aR2,aR3, sA0,sA1,qB0,qB1); \
  ldA2<2>(sA0,sA1, wa,wb,(b6)+6); ldB2<2>(qB0,qB1, LDBP0,LDBP1,(b6)+5); mm_22<2>(aR0,aR1,aR2,aR3, tA0,tA1,pB0,pB1); \
  ldA2<2>(tA0,tA1, wa,wb,(b6)+7); ldB2<2>(pB0,pB1, LDBP0,LDBP1,(b6)+6); mm_22<2>(aR0,aR1,aR2,aR3, uA0,uA1,qB0,qB1);

// ---------- fused main kernel: linear 8-barrier chain, chunk-512 L0/L1, 3A/2B pipeline ----------
__global__ __launch_bounds__(512, 2) void jiif_main(
    const float* __restrict__ coord,
    const _Float16* __restrict__ featT, const _Float16* __restrict__ hrT,
    const _Float16* __restrict__ lrT,
    const _Float16* __restrict__ W0p, const _Float16* __restrict__ W1p,
    const _Float16* __restrict__ W2p, const _Float16* __restrict__ W3p,
    const float* __restrict__ b0, const float* __restrict__ b1,
    const float* __restrict__ b2, const float* __restrict__ b3,
    const float* __restrict__ W4, const float* __restrict__ b4,
    float* __restrict__ preds) {
  extern __shared__ _Float16 lds[];
  const int tid = threadIdx.x;
  const int w = tid >> 6, lane = tid & 63;
  const int m0 = blockIdx.x * MROWS;
  _Float16* X   = lds;             // [64][SX]
  _Float16* Hc  = lds + OFF_HC;    // [64][SHC]
  _Float16* H2r = lds;             // [64][S2H]  (overlays X + Hc rows 0..7, after b5)
  _Float16* H3r = lds + OFF_H3;    // [64][S3]   (virgin region)
  _Float16* H4r = lds;             // [64][S4]   (overlays H2 head, after b7)

  // ---- gather: build X[64][448] (cols 386..447 zero) ----
  {
    const int r = tid >> 3;       // 0..63
    const int g = tid & 7;        // 8 threads per row
    const int row = m0 + r;
    const int n = row & (NN - 1);
    const int bb = (row >> 14) & (BN - 1);
    const int k = row >> 15;      // offset index 0..3
    const float c0 = coord[((size_t)bb * NN + n) * 2 + 0];
    const float c1 = coord[((size_t)bb * NN + n) * 2 + 1];
    const float cy = c0 + ((k < 2) ? -1.f : 1.f) * (1.f / FH);
    const float cx = c1 + ((k & 1) ? 1.f : -1.f) * (1.f / FW);
    const float fy = rintf((cy + 1.f) * (FH * 0.5f) - 0.5f);
    const float fx = rintf((cx + 1.f) * (FW * 0.5f) - 0.5f);
    const bool vF = (fy >= 0.f) && (fy < (float)FH) && (fx >= 0.f) && (fx < (float)FW);
    const int iy = max(0, min(FH - 1, (int)fy));
    const int ix = max(0, min(FW - 1, (int)fx));
    const float gy = rintf((c0 + 1.f) * (GH * 0.5f) - 0.5f);
    const float gx = rintf((c1 + 1.f) * (GW * 0.5f) - 0.5f);
    const bool vH = (gy >= 0.f) && (gy < (float)GH) && (gx >= 0.f) && (gx < (float)GW);
    const int jy = max(0, min(GH - 1, (int)gy));
    const int jx = max(0, min(GW - 1, (int)gx));
    const _Float16* fp = featT + (size_t)((bb * FH + iy) * FW + ix) * CC;
    const _Float16* lp = lrT  + (size_t)((bb * FH + iy) * FW + ix) * CC;
    const _Float16* hp = hrT  + (size_t)((bb * GH + jy) * GW + jx) * CC;
    _Float16* xr = X + (size_t)r * SX;
#pragma unroll
    for (int t = 0; t < 2; ++t) {
      const int c8 = g * 16 + t * 8;
      half8 fv = vF ? *(const half8*)(fp + c8) : zero8();
      half8 lv = vF ? *(const half8*)(lp + c8) : zero8();
      half8 hv = vH ? *(const half8*)(hp + c8) : zero8();
      *(half8*)(xr + c8) = fv;
      *(half8*)(xr + CC + c8) = hv;
      half8 dv = hv - lv;
      *(half8*)(xr + 2 * CC + c8) = dv;
    }
    *(unsigned long long*)(xr + 384 + g * 8) = 0ull;
    *(unsigned long long*)(xr + 384 + g * 8 + 4) = 0ull;
    if (g == 0) {
      const float qc0 = vF ? (-1.f + (float)(2 * iy + 1) * (1.f / FH)) : 0.f;
      const float qc1 = vF ? (-1.f + (float)(2 * ix + 1) * (1.f / FW)) : 0.f;
      xr[384] = (_Float16)((c0 - qc0) * (float)FH);
      xr[385] = (_Float16)((c1 - qc1) * (float)FW);
    }
  }
  __syncthreads();   // b1

  const int m31 = lane & 31;
  const int s8 = (lane >> 5) * 8;
  const _Float16* xb0 = X + (size_t)m31 * SX + s8;
  const _Float16* xb1 = xb0 + 32 * SX;
  const _Float16* hb0 = Hc + (size_t)m31 * SHC + s8;
  const _Float16* hb1 = hb0 + 32 * SHC;

  // ================= L0 chunk0: j-tiles {2w,2w+1}, 14 batch2, 3A/2B =================
  {
    f32x16 aR0 = zero16(), aR1 = zero16(), aR2 = zero16(), aR3 = zero16();
    const _Float16* wa = W0p + ((size_t)(2 * w) * 28 * 64 + lane) * 8;
    const _Float16* wb = wa + 28 * 512;
    half8 sA0[2], sA1[2], tA0[2], tA1[2], uA0[2], uA1[2];
    half8 pB0[2], pB1[2], qB0[2], qB1[2];
    ldA2<2>(sA0, sA1, wa, wb, 0);
    ldA2<2>(tA0, tA1, wa, wb, 1);
    ldB2<2>(pB0, pB1, xb0, xb1, 0);
#pragma unroll 1
    for (int b6 = 0; b6 < 12; b6 += 6) { ROLL6_22(b6, xb0, xb1) }
    // tail u=12,13 (A12->sA, A13->tA, B12->pB already resident)
    ldB2<2>(qB0, qB1, xb0, xb1, 13); mm_22<2>(aR0, aR1, aR2, aR3, sA0, sA1, pB0, pB1);
    mm_22<2>(aR0, aR1, aR2, aR3, tA0, tA1, qB0, qB1);
    store_tile<true>(aR0, Hc, SHC, 0,  (2 * w) * 32,     b0 + (2 * w) * 32,     lane);
    store_tile<true>(aR1, Hc, SHC, 32, (2 * w) * 32,     b0 + (2 * w) * 32,     lane);
    store_tile<true>(aR2, Hc, SHC, 0,  (2 * w + 1) * 32, b0 + (2 * w + 1) * 32, lane);
    store_tile<true>(aR3, Hc, SHC, 32, (2 * w + 1) * 32, b0 + (2 * w + 1) * 32, lane);
  }
  __syncthreads();   // b2

  // ================= L1 chunk0: K 0..511 from Hc, 16 batch2, 3A/2B =================
  f32x16 a2_00 = zero16(), a2_01 = zero16(), a2_10 = zero16(), a2_11 = zero16();
  const _Float16* w1a = W1p + ((size_t)(2 * w) * 64 * 64 + lane) * 8;
  const _Float16* w1b = w1a + 64 * 512;                                  // jt+1
  {
    f32x16& aR0 = a2_00; f32x16& aR1 = a2_01; f32x16& aR2 = a2_10; f32x16& aR3 = a2_11;
    const _Float16* wa = w1a;
    const _Float16* wb = w1b;
    half8 sA0[2], sA1[2], tA0[2], tA1[2], uA0[2], uA1[2];
    half8 pB0[2], pB1[2], qB0[2], qB1[2];
    ldA2<2>(sA0, sA1, wa, wb, 0);
    ldA2<2>(tA0, tA1, wa, wb, 1);
    ldB2<2>(pB0, pB1, hb0, hb1, 0);
#pragma unroll 1
    for (int b6 = 0; b6 < 12; b6 += 6) { ROLL6_22(b6, hb0, hb1) }
    // tail u=12..15
    ldA2<2>(uA0, uA1, wa, wb, 14); ldB2<2>(qB0, qB1, hb0, hb1, 13); mm_22<2>(aR0, aR1, aR2, aR3, sA0, sA1, pB0, pB1);
    ldA2<2>(sA0, sA1, wa, wb, 15); ldB2<2>(pB0, pB1, hb0, hb1, 14); mm_22<2>(aR0, aR1, aR2, aR3, tA0, tA1, qB0, qB1);
    ldB2<2>(qB0, qB1, hb0, hb1, 15); mm_22<2>(aR0, aR1, aR2, aR3, uA0, uA1, pB0, pB1);
    mm_22<2>(aR0, aR1, aR2, aR3, sA0, sA1, qB0, qB1);
  }
  __syncthreads();   // b3

  // ================= L0 chunk1: j-tiles {16+2w,16+2w+1}, 14 batch2, 3A/2B =================
  {
    f32x16 aR0 = zero16(), aR1 = zero16(), aR2 = zero16(), aR3 = zero16();
    const _Float16* wa = W0p + ((size_t)(16 + 2 * w) * 28 * 64 + lane) * 8;
    const _Float16* wb = wa + 28 * 512;
    half8 sA0[2], sA1[2], tA0[2], tA1[2], uA0[2], uA1[2];
    half8 pB0[2], pB1[2], qB0[2], qB1[2];
    ldA2<2>(sA0, sA1, wa, wb, 0);
    ldA2<2>(tA0, tA1, wa, wb, 1);
    ldB2<2>(pB0, pB1, xb0, xb1, 0);
#pragma unroll 1
    for (int b6 = 0; b6 < 12; b6 += 6) { ROLL6_22(b6, xb0, xb1) }
    ldB2<2>(qB0, qB1, xb0, xb1, 13); mm_22<2>(aR0, aR1, aR2, aR3, sA0, sA1, pB0, pB1);
    mm_22<2>(aR0, aR1, aR2, aR3, tA0, tA1, qB0, qB1);
    store_tile<true>(aR0, Hc, SHC, 0,  (2 * w) * 32,     b0 + 512 + (2 * w) * 32,     lane);
    store_tile<true>(aR1, Hc, SHC, 32, (2 * w) * 32,     b0 + 512 + (2 * w) * 32,     lane);
    store_tile<true>(aR2, Hc, SHC, 0,  (2 * w + 1) * 32, b0 + 512 + (2 * w + 1) * 32, lane);
    store_tile<true>(aR3, Hc, SHC, 32, (2 * w + 1) * 32, b0 + 512 + (2 * w + 1) * 32, lane);
  }
  __syncthreads();   // b4

  // ================= L1 chunk1: K 512..1023 (weight kt 32..63), 16 batch2, 3A/2B =================
  {
    f32x16& aR0 = a2_00; f32x16& aR1 = a2_01; f32x16& aR2 = a2_10; f32x16& aR3 = a2_11;
    const _Float16* wa = w1a + 32 * 512;
    const _Float16* wb = w1b + 32 * 512;
    half8 sA0[2], sA1[2], tA0[2], tA1[2], uA0[2], uA1[2];
    half8 pB0[2], pB1[2], qB0[2], qB1[2];
    ldA2<2>(sA0, sA1, wa, wb, 0);
    ldA2<2>(tA0, tA1, wa, wb, 1);
    ldB2<2>(pB0, pB1, hb0, hb1, 0);
#pragma unroll 1
    for (int b6 = 0; b6 < 12; b6 += 6) { ROLL6_22(b6, hb0, hb1) }
    ldA2<2>(uA0, uA1, wa, wb, 14); ldB2<2>(qB0, qB1, hb0, hb1, 13); mm_22<2>(aR0, aR1, aR2, aR3, sA0, sA1, pB0, pB1);
    ldA2<2>(sA0, sA1, wa, wb, 15); ldB2<2>(pB0, pB1, hb0, hb1, 14); mm_22<2>(aR0, aR1, aR2, aR3, tA0, tA1, qB0, qB1);
    ldB2<2>(qB0, qB1, hb0, hb1, 15); mm_22<2>(aR0, aR1, aR2, aR3, uA0, uA1, pB0, pB1);
    mm_22<2>(aR0, aR1, aR2, aR3, sA0, sA1, qB0, qB1);
  }
  __syncthreads();   // b5 (all X/Hc reads complete)

  // ---- H2 stores (overlay X + Hc rows 0..7) ----
  store_tile<true>(a2_00, H2r, S2H, 0,  (2 * w) * 32,     b1 + (2 * w) * 32,     lane);
  store_tile<true>(a2_01, H2r, S2H, 32, (2 * w) * 32,     b1 + (2 * w) * 32,     lane);
  store_tile<true>(a2_10, H2r, S2H, 0,  (2 * w + 1) * 32, b1 + (2 * w + 1) * 32, lane);
  store_tile<true>(a2_11, H2r, S2H, 32, (2 * w + 1) * 32, b1 + (2 * w + 1) * 32, lane);
  __syncthreads();   // b6

  // ================= L2: K=512 -> 256, j2=w, 2mt, 16 batch2, 3A/2B =================
  {
    const _Float16* wb2 = W2p + ((size_t)w * 32 * 64 + lane) * 8;
    const _Float16* h2b0 = H2r + (size_t)m31 * S2H + s8;
    const _Float16* h2b1 = h2b0 + 32 * S2H;
    f32x16 a3lo = zero16(), a3hi = zero16();
    half8 sA[2], tA[2], uA[2];
    half8 pB0[2], pB1[2], qB0[2], qB1[2];
    ldA1<2>(sA, wb2, 0);
    ldA1<2>(tA, wb2, 1);
    ldB2<2>(pB0, pB1, h2b0, h2b1, 0);
#pragma unroll 1
    for (int b6 = 0; b6 < 12; b6 += 6) {
      ldA1<2>(uA, wb2, b6 + 2); ldB2<2>(qB0, qB1, h2b0, h2b1, b6 + 1); mm_12<2>(a3lo, a3hi, sA, pB0, pB1);
      ldA1<2>(sA, wb2, b6 + 3); ldB2<2>(pB0, pB1, h2b0, h2b1, b6 + 2); mm_12<2>(a3lo, a3hi, tA, qB0, qB1);
      ldA1<2>(tA, wb2, b6 + 4); ldB2<2>(qB0, qB1, h2b0, h2b1, b6 + 3); mm_12<2>(a3lo, a3hi, uA, pB0, pB1);
      ldA1<2>(uA, wb2, b6 + 5); ldB2<2>(pB0, pB1, h2b0, h2b1, b6 + 4); mm_12<2>(a3lo, a3hi, sA, qB0, qB1);
      ldA1<2>(sA, wb2, b6 + 6); ldB2<2>(qB0, qB1, h2b0, h2b1, b6 + 5); mm_12<2>(a3lo, a3hi, tA, pB0, pB1);
      ldA1<2>(tA, wb2, b6 + 7); ldB2<2>(pB0, pB1, h2b0, h2b1, b6 + 6); mm_12<2>(a3lo, a3hi, uA, qB0, qB1);
    }
    // tail u=12..15
    ldA1<2>(uA, wb2, 14); ldB2<2>(qB0, qB1, h2b0, h2b1, 13); mm_12<2>(a3lo, a3hi, sA, pB0, pB1);
    ldA1<2>(sA, wb2, 15); ldB2<2>(pB0, pB1, h2b0, h2b1, 14); mm_12<2>(a3lo, a3hi, tA, qB0, qB1);
    ldB2<2>(qB0, qB1, h2b0, h2b1, 15); mm_12<2>(a3lo, a3hi, uA, pB0, pB1);
    mm_12<2>(a3lo, a3hi, sA, qB0, qB1);
    // H3 region overlaps nothing -> safe to store before barrier
    store_tile<true>(a3lo, H3r, S3, 0,  w * 32, b2 + w * 32, lane);
    store_tile<true>(a3hi, H3r, S3, 32, w * 32, b2 + w * 32, lane);
  }
  __syncthreads();   // b7 (all H2 reads done)

  // ================= L3: K=256 -> 128, j3=w&3, mt=w>>2, 16 kt, batch4 2-deep =================
  {
    const int j3 = w & 3, mts = w >> 2;
    const _Float16* wb3 = W3p + ((size_t)j3 * 16 * 64 + lane) * 8;
    const _Float16* h3b = H3r + (size_t)(mts * 32 + m31) * S3 + s8;
    f32x16 a4 = zero16();
    half8 sA[4], sB[4], tA[4], tB[4];
    ldA1<4>(sA, wb3, 0); ldB1<4>(sB, h3b, 0);
    ldA1<4>(tA, wb3, 1); ldB1<4>(tB, h3b, 1);
    mm_11<4>(a4, sA, sB);
    ldA1<4>(sA, wb3, 2); ldB1<4>(sB, h3b, 2);
    mm_11<4>(a4, tA, tB);
    ldA1<4>(tA, wb3, 3); ldB1<4>(tB, h3b, 3);
    mm_11<4>(a4, sA, sB);
    mm_11<4>(a4, tA, tB);
    store_tile<true>(a4, H4r, S4, mts * 32, j3 * 32, b3 + j3 * 32, lane);
  }
  __syncthreads();   // b8

  // ---- L4: [64][128] @ W4^T -> [64][2] ----
  {
    const int m = tid >> 3;
    const int sub = tid & 7;
    const int j = sub & 1;
    const int q = sub >> 1;
    const _Float16* h4 = H4r + (size_t)m * S4 + q * 32;
    const float* w4 = W4 + j * CC + q * 32;
    float s = 0.f;
#pragma unroll
    for (int cc = 0; cc < 32; ++cc) s += (float)h4[cc] * w4[cc];
    s += __shfl_xor(s, 2);
    s += __shfl_xor(s, 4);
    if (q == 0) preds[(size_t)(m0 + m) * 2 + j] = s + b4[j];
  }
}

// ---------- softmax-combine over the 4 samples ----------
__global__ void jiif_combine(const float* __restrict__ preds, float* __restrict__ out) {
  const int i = blockIdx.x * 256 + threadIdx.x;
  if (i >= BN * NN) return;
  float p0[4], p1[4];
#pragma unroll
  for (int k = 0; k < 4; ++k) {
    p0[k] = preds[((size_t)k * BN * NN + i) * 2 + 0];
    p1[k] = preds[((size_t)k * BN * NN + i) * 2 + 1];
  }
  float mx = fmaxf(fmaxf(p1[0], p1[1]), fmaxf(p1[2], p1[3]));
  float se = 0.f, so = 0.f;
#pragma unroll
  for (int k = 0; k < 4; ++k) {
    float e = expf(p1[k] - mx);
    se += e;
    so += p0[k] * e;
  }
  out[i] = so / se;
}

extern "C" void kernel_launch(void* const* d_in, const int* in_sizes, int n_in,
                              void* d_out, int out_size, void* d_ws, size_t ws_size,
                              hipStream_t stream) {
  const float* feat  = (const float*)d_in[0];
  const float* coord = (const float*)d_in[1];
  const float* hr    = (const float*)d_in[2];
  const float* lr    = (const float*)d_in[3];
  const float* W0 = (const float*)d_in[4];  const float* b0 = (const float*)d_in[5];
  const float* W1 = (const float*)d_in[6];  const float* b1 = (const float*)d_in[7];
  const float* W2 = (const float*)d_in[8];  const float* b2 = (const float*)d_in[9];
  const float* W3 = (const float*)d_in[10]; const float* b3 = (const float*)d_in[11];
  const float* W4 = (const float*)d_in[12]; const float* b4 = (const float*)d_in[13];

  char* ws = (char*)d_ws;
  _Float16* W0p   = (_Float16*)(ws + 0);          // 32*28*512*2  =   917504
  _Float16* W1p   = (_Float16*)(ws + 917504);     // 16*64*512*2  =  1048576
  _Float16* W2p   = (_Float16*)(ws + 1966080);    // 8*32*512*2   =   262144
  _Float16* W3p   = (_Float16*)(ws + 2228224);    // 4*16*512*2   =    65536
  _Float16* featT = (_Float16*)(ws + 2293760);    // 2097152
  _Float16* hrT   = (_Float16*)(ws + 4390912);    // 33554432
  _Float16* lrT   = (_Float16*)(ws + 37945344);   // 2097152
  float* preds    = (float*)(ws + 40042496);      // 1048576 -> total 41091072
  if (ws_size < 41091072) return;

  pack_w<<<224, 256, 0, stream>>>(W0, W0p, 32, 386, 28);
  pack_w<<<256, 256, 0, stream>>>(W1, W1p, 16, 1024, 64);
  pack_w<<<64,  256, 0, stream>>>(W2, W2p, 8, 512, 32);
  pack_w<<<16,  256, 0, stream>>>(W3, W3p, 4, 256, 16);

  transpose_to_hwc<<<dim3(2, 4, 128), dim3(32, 8), 0, stream>>>(feat, featT, CC, FH, FW);
  transpose_to_hwc<<<dim3(8, 4, 512), dim3(32, 8), 0, stream>>>(hr,   hrT,   CC, GH, GW);
  transpose_to_hwc<<<dim3(2, 4, 128), dim3(32, 8), 0, stream>>>(lr,   lrT,   CC, FH, FW);

  (void)hipFuncSetAttribute((const void*)jiif_main,
                            hipFuncAttributeMaxDynamicSharedMemorySize, LDS_ELEMS * 2);
  jiif_main<<<NBLK, 512, LDS_ELEMS * 2, stream>>>(
      coord, featT, hrT, lrT, W0p, W1p, W2p, W3p, b0, b1, b2, b3, W4, b4, preds);

  jiif_combine<<<(BN * NN + 255) / 256, 256, 0, stream>>>(preds, (float*)d_out);
}

// Round 13
// 356.895 us; speedup vs baseline: 1.2680x; 1.2680x over previous
//
#include <hip/hip_runtime.h>
#include <cstdint>

typedef __attribute__((ext_vector_type(8))) _Float16 half8;   // 8 fp16 = 4 VGPRs
typedef __attribute__((ext_vector_type(16))) float   f32x16;  // 32x32 MFMA acc

#define BN 2
#define NN 16384
#define FH 64
#define FW 64
#define GH 256
#define GW 256
#define CC 128
#define M_TOTAL (4*BN*NN)    // 131072
#define MROWS 64
#define NBLK (M_TOTAL/MROWS) // 2048

// LDS strides (fp16 elems)
#define SX  456              // X [64][448+pad]
#define SHC 520              // Hc (H1 512-col chunk) [64][512+pad]
#define S2H 520              // H2 [64][512+pad]
#define S3  264              // H3 [64][256+pad]
#define S4  136              // H4 [64][128+pad]
#define OFF_HC 29184         // 64*SX ; Hc spans [29184, 62464)
#define OFF_H3 62464         // virgin region after Hc ; H3 spans [62464, 79360)
#define LDS_ELEMS 79360      // 158720 B <= 160 KiB -> 1 block/CU

#define MFMA(a,b,c) __builtin_amdgcn_mfma_f32_32x32x16_f16((a),(b),(c),0,0,0)

static __device__ __forceinline__ f32x16 zero16() {
  f32x16 z;
#pragma unroll
  for (int i = 0; i < 16; ++i) z[i] = 0.f;
  return z;
}
static __device__ __forceinline__ half8 zero8() {
  half8 z;
#pragma unroll
  for (int e = 0; e < 8; ++e) z[e] = (_Float16)0.f;
  return z;
}

// ---- staging loads (batch NB kt). Arch-VGPR budget ~128 (accs live in AGPR half
// of the unified file): keep per-phase staging <= 64 arch regs -> batch-2
// double-buffered everywhere except L3 (batch-4, single-A). Deeper staging (R8/R12)
// or more waves (R11) both spill -> this is the empirically optimal point.
template<int NB>
static __device__ __forceinline__ void ldA2(half8 (&A0)[NB], half8 (&A1)[NB],
    const _Float16* wa, const _Float16* wb, int t) {
#pragma unroll
  for (int i = 0; i < NB; ++i) {
    const int kt = t * NB + i;
    A0[i] = *(const half8*)(wa + kt * 512);
    A1[i] = *(const half8*)(wb + kt * 512);
  }
}
template<int NB>
static __device__ __forceinline__ void ldA1(half8 (&A)[NB], const _Float16* wa, int t) {
#pragma unroll
  for (int i = 0; i < NB; ++i) A[i] = *(const half8*)(wa + (t * NB + i) * 512);
}
template<int NB>
static __device__ __forceinline__ void ldB2(half8 (&B0)[NB], half8 (&B1)[NB],
    const _Float16* p0, const _Float16* p1, int t) {
#pragma unroll
  for (int i = 0; i < NB; ++i) {
    const int kt = t * NB + i;
    B0[i] = *(const half8*)(p0 + kt * 16);
    B1[i] = *(const half8*)(p1 + kt * 16);
  }
}
template<int NB>
static __device__ __forceinline__ void ldB1(half8 (&B)[NB], const _Float16* p, int t) {
#pragma unroll
  for (int i = 0; i < NB; ++i) B[i] = *(const half8*)(p + (t * NB + i) * 16);
}

// ---- pinned MFMA bursts ----
template<int NB>
static __device__ __forceinline__ void mm_22(f32x16& a00, f32x16& a01, f32x16& a10, f32x16& a11,
    const half8 (&A0)[NB], const half8 (&A1)[NB], const half8 (&B0)[NB], const half8 (&B1)[NB]) {
  __builtin_amdgcn_sched_barrier(0);
  __builtin_amdgcn_s_setprio(1);
#pragma unroll
  for (int i = 0; i < NB; ++i) {
    a00 = MFMA(A0[i], B0[i], a00);
    a01 = MFMA(A0[i], B1[i], a01);
    a10 = MFMA(A1[i], B0[i], a10);
    a11 = MFMA(A1[i], B1[i], a11);
  }
  __builtin_amdgcn_s_setprio(0);
  __builtin_amdgcn_sched_barrier(0);
}
template<int NB>
static __device__ __forceinline__ void mm_12(f32x16& lo, f32x16& hi,
    const half8 (&A)[NB], const half8 (&B0)[NB], const half8 (&B1)[NB]) {
  __builtin_amdgcn_sched_barrier(0);
  __builtin_amdgcn_s_setprio(1);
#pragma unroll
  for (int i = 0; i < NB; ++i) {
    lo = MFMA(A[i], B0[i], lo);
    hi = MFMA(A[i], B1[i], hi);
  }
  __builtin_amdgcn_s_setprio(0);
  __builtin_amdgcn_sched_barrier(0);
}
template<int NB>
static __device__ __forceinline__ void mm_11(f32x16& acc,
    const half8 (&A)[NB], const half8 (&B)[NB]) {
  __builtin_amdgcn_sched_barrier(0);
  __builtin_amdgcn_s_setprio(1);
#pragma unroll
  for (int i = 0; i < NB; ++i) acc = MFMA(A[i], B[i], acc);
  __builtin_amdgcn_s_setprio(0);
  __builtin_amdgcn_sched_barrier(0);
}

// ---------- weight fp32 -> packed fp16 32x16 MFMA A-fragment tiles ----------
__global__ void pack_w(const float* __restrict__ wsrc, _Float16* __restrict__ out,
                       int NT, int K, int KT) {   // NT = NOUT/32
  int idx = blockIdx.x * 256 + threadIdx.x;
  int total = NT * KT * 64;
  if (idx >= total) return;
  int l = idx & 63;
  int t = idx >> 6;
  int kt = t % KT;
  int jt = t / KT;
  int row = jt * 32 + (l & 31);
  int k0 = kt * 16 + (l >> 5) * 8;
  _Float16* o = out + (size_t)idx * 8;
#pragma unroll
  for (int e = 0; e < 8; ++e) {
    int k = k0 + e;
    float v = (k < K) ? wsrc[(size_t)row * K + k] : 0.f;
    o[e] = (_Float16)v;
  }
}

// ---------- CHW -> HWC fp16 transpose ----------
__global__ void transpose_to_hwc(const float* __restrict__ in, _Float16* __restrict__ out,
                                 int C, int HH, int WW) {
  __shared__ float tile[32][33];
  const int xt = blockIdx.x, ct = blockIdx.y;
  const int bb = blockIdx.z / HH, y = blockIdx.z % HH;
  const int tx = threadIdx.x, ty = threadIdx.y;
  const int x0 = xt * 32, c0 = ct * 32;
#pragma unroll
  for (int i = 0; i < 4; ++i) {
    int c = c0 + ty + i * 8;
    tile[ty + i * 8][tx] = in[((size_t)(bb * C + c) * HH + y) * WW + x0 + tx];
  }
  __syncthreads();
#pragma unroll
  for (int i = 0; i < 4; ++i) {
    int x = x0 + ty + i * 8;
    out[((size_t)(bb * HH + y) * WW + x) * C + c0 + tx] = (_Float16)tile[tx][ty + i * 8];
  }
}

// ---------- store one 32x32 D-tile to LDS, bias+relu, 8B-vectorized ----------
// D layout (A=W, B=acts): act-row m = lane&31, out-ch n = (reg&3)+8*(reg>>2)+4*(lane>>5)
template<bool RELU>
static __device__ __forceinline__ void store_tile(const f32x16 acc, _Float16* lout, int ldo,
                                                  int row0, int col0,
                                                  const float* __restrict__ biasBase, int lane) {
  const int m = row0 + (lane & 31);
  const int s4 = (lane >> 5) * 4;
  _Float16* rp = lout + (size_t)m * ldo + col0 + s4;
  const float* bp = biasBase + s4;
#pragma unroll
  for (int g = 0; g < 4; ++g) {
    float4 bv = *(const float4*)(bp + 8 * g);
    union { _Float16 h[4]; unsigned long long u; } pk;
#pragma unroll
    for (int e = 0; e < 4; ++e) {
      float v = acc[4 * g + e] + ((const float*)&bv)[e];
      if (RELU) v = fmaxf(v, 0.f);
      pk.h[e] = (_Float16)v;
    }
    *(unsigned long long*)(rp + 8 * g) = pk.u;
  }
}

// ---------- fused main kernel: linear 8-barrier chain, chunk-512 L0/L1, batch-2 staging ----------
__global__ __launch_bounds__(512, 2) void jiif_main(
    const float* __restrict__ coord,
    const _Float16* __restrict__ featT, const _Float16* __restrict__ hrT,
    const _Float16* __restrict__ lrT,
    const _Float16* __restrict__ W0p, const _Float16* __restrict__ W1p,
    const _Float16* __restrict__ W2p, const _Float16* __restrict__ W3p,
    const float* __restrict__ b0, const float* __restrict__ b1,
    const float* __restrict__ b2, const float* __restrict__ b3,
    const float* __restrict__ W4, const float* __restrict__ b4,
    float* __restrict__ preds) {
  extern __shared__ _Float16 lds[];
  const int tid = threadIdx.x;
  const int w = tid >> 6, lane = tid & 63;
  const int m0 = blockIdx.x * MROWS;
  _Float16* X   = lds;             // [64][SX]
  _Float16* Hc  = lds + OFF_HC;    // [64][SHC]
  _Float16* H2r = lds;             // [64][S2H]  (overlays X + Hc rows 0..7, after b5)
  _Float16* H3r = lds + OFF_H3;    // [64][S3]   (virgin region)
  _Float16* H4r = lds;             // [64][S4]   (overlays H2 head, after b7)

  // ---- gather: build X[64][448] (cols 386..447 zero) ----
  {
    const int r = tid >> 3;       // 0..63
    const int g = tid & 7;        // 8 threads per row
    const int row = m0 + r;
    const int n = row & (NN - 1);
    const int bb = (row >> 14) & (BN - 1);
    const int k = row >> 15;      // offset index 0..3
    const float c0 = coord[((size_t)bb * NN + n) * 2 + 0];
    const float c1 = coord[((size_t)bb * NN + n) * 2 + 1];
    const float cy = c0 + ((k < 2) ? -1.f : 1.f) * (1.f / FH);
    const float cx = c1 + ((k & 1) ? 1.f : -1.f) * (1.f / FW);
    const float fy = rintf((cy + 1.f) * (FH * 0.5f) - 0.5f);
    const float fx = rintf((cx + 1.f) * (FW * 0.5f) - 0.5f);
    const bool vF = (fy >= 0.f) && (fy < (float)FH) && (fx >= 0.f) && (fx < (float)FW);
    const int iy = max(0, min(FH - 1, (int)fy));
    const int ix = max(0, min(FW - 1, (int)fx));
    const float gy = rintf((c0 + 1.f) * (GH * 0.5f) - 0.5f);
    const float gx = rintf((c1 + 1.f) * (GW * 0.5f) - 0.5f);
    const bool vH = (gy >= 0.f) && (gy < (float)GH) && (gx >= 0.f) && (gx < (float)GW);
    const int jy = max(0, min(GH - 1, (int)gy));
    const int jx = max(0, min(GW - 1, (int)gx));
    const _Float16* fp = featT + (size_t)((bb * FH + iy) * FW + ix) * CC;
    const _Float16* lp = lrT  + (size_t)((bb * FH + iy) * FW + ix) * CC;
    const _Float16* hp = hrT  + (size_t)((bb * GH + jy) * GW + jx) * CC;
    _Float16* xr = X + (size_t)r * SX;
#pragma unroll
    for (int t = 0; t < 2; ++t) {
      const int c8 = g * 16 + t * 8;
      half8 fv = vF ? *(const half8*)(fp + c8) : zero8();
      half8 lv = vF ? *(const half8*)(lp + c8) : zero8();
      half8 hv = vH ? *(const half8*)(hp + c8) : zero8();
      *(half8*)(xr + c8) = fv;
      *(half8*)(xr + CC + c8) = hv;
      half8 dv = hv - lv;
      *(half8*)(xr + 2 * CC + c8) = dv;
    }
    *(unsigned long long*)(xr + 384 + g * 8) = 0ull;
    *(unsigned long long*)(xr + 384 + g * 8 + 4) = 0ull;
    if (g == 0) {
      const float qc0 = vF ? (-1.f + (float)(2 * iy + 1) * (1.f / FH)) : 0.f;
      const float qc1 = vF ? (-1.f + (float)(2 * ix + 1) * (1.f / FW)) : 0.f;
      xr[384] = (_Float16)((c0 - qc0) * (float)FH);
      xr[385] = (_Float16)((c1 - qc1) * (float)FW);
    }
  }
  __syncthreads();   // b1

  const int m31 = lane & 31;
  const int s8 = (lane >> 5) * 8;
  const _Float16* xb0 = X + (size_t)m31 * SX + s8;
  const _Float16* xb1 = xb0 + 32 * SX;
  const _Float16* hb0 = Hc + (size_t)m31 * SHC + s8;
  const _Float16* hb1 = hb0 + 32 * SHC;

  // ================= L0 chunk0: j-tiles {2w,2w+1}, 28 kt, batch2 2-deep =================
  {
    f32x16 a00 = zero16(), a01 = zero16(), a10 = zero16(), a11 = zero16();
    const _Float16* wa = W0p + ((size_t)(2 * w) * 28 * 64 + lane) * 8;
    const _Float16* wb = wa + 28 * 512;
    half8 pA0[2], pA1[2], pB0[2], pB1[2], qA0[2], qA1[2], qB0[2], qB1[2];
    ldA2<2>(pA0, pA1, wa, wb, 0); ldB2<2>(pB0, pB1, xb0, xb1, 0);
    ldA2<2>(qA0, qA1, wa, wb, 1); ldB2<2>(qB0, qB1, xb0, xb1, 1);
#pragma unroll 1
    for (int u = 0; u < 6; ++u) {
      mm_22<2>(a00, a01, a10, a11, pA0, pA1, pB0, pB1);
      ldA2<2>(pA0, pA1, wa, wb, 2 * u + 2); ldB2<2>(pB0, pB1, xb0, xb1, 2 * u + 2);
      mm_22<2>(a00, a01, a10, a11, qA0, qA1, qB0, qB1);
      ldA2<2>(qA0, qA1, wa, wb, 2 * u + 3); ldB2<2>(qB0, qB1, xb0, xb1, 2 * u + 3);
    }
    mm_22<2>(a00, a01, a10, a11, pA0, pA1, pB0, pB1);
    mm_22<2>(a00, a01, a10, a11, qA0, qA1, qB0, qB1);
    store_tile<true>(a00, Hc, SHC, 0,  (2 * w) * 32,     b0 + (2 * w) * 32,     lane);
    store_tile<true>(a01, Hc, SHC, 32, (2 * w) * 32,     b0 + (2 * w) * 32,     lane);
    store_tile<true>(a10, Hc, SHC, 0,  (2 * w + 1) * 32, b0 + (2 * w + 1) * 32, lane);
    store_tile<true>(a11, Hc, SHC, 32, (2 * w + 1) * 32, b0 + (2 * w + 1) * 32, lane);
  }
  __syncthreads();   // b2

  // ================= L1 chunk0: K 0..511 from Hc, 32 kt = 16 batch2, 2-deep =================
  f32x16 a2_00 = zero16(), a2_01 = zero16(), a2_10 = zero16(), a2_11 = zero16();
  const _Float16* w1a = W1p + ((size_t)(2 * w) * 64 * 64 + lane) * 8;
  const _Float16* w1b = w1a + 64 * 512;                                  // jt+1
  {
    half8 sA0[2], sA1[2], sB0[2], sB1[2], tA0[2], tA1[2], tB0[2], tB1[2];
    ldA2<2>(sA0, sA1, w1a, w1b, 0); ldB2<2>(sB0, sB1, hb0, hb1, 0);
    ldA2<2>(tA0, tA1, w1a, w1b, 1); ldB2<2>(tB0, tB1, hb0, hb1, 1);
#pragma unroll 1
    for (int u = 0; u < 7; ++u) {
      mm_22<2>(a2_00, a2_01, a2_10, a2_11, sA0, sA1, sB0, sB1);
      ldA2<2>(sA0, sA1, w1a, w1b, 2 * u + 2); ldB2<2>(sB0, sB1, hb0, hb1, 2 * u + 2);
      mm_22<2>(a2_00, a2_01, a2_10, a2_11, tA0, tA1, tB0, tB1);
      ldA2<2>(tA0, tA1, w1a, w1b, 2 * u + 3); ldB2<2>(tB0, tB1, hb0, hb1, 2 * u + 3);
    }
    mm_22<2>(a2_00, a2_01, a2_10, a2_11, sA0, sA1, sB0, sB1);
    mm_22<2>(a2_00, a2_01, a2_10, a2_11, tA0, tA1, tB0, tB1);
  }
  __syncthreads();   // b3

  // ================= L0 chunk1: j-tiles {16+2w,16+2w+1}, 28 kt, batch2 2-deep =================
  {
    f32x16 a00 = zero16(), a01 = zero16(), a10 = zero16(), a11 = zero16();
    const _Float16* wa = W0p + ((size_t)(16 + 2 * w) * 28 * 64 + lane) * 8;
    const _Float16* wb = wa + 28 * 512;
    half8 pA0[2], pA1[2], pB0[2], pB1[2], qA0[2], qA1[2], qB0[2], qB1[2];
    ldA2<2>(pA0, pA1, wa, wb, 0); ldB2<2>(pB0, pB1, xb0, xb1, 0);
    ldA2<2>(qA0, qA1, wa, wb, 1); ldB2<2>(qB0, qB1, xb0, xb1, 1);
#pragma unroll 1
    for (int u = 0; u < 6; ++u) {
      mm_22<2>(a00, a01, a10, a11, pA0, pA1, pB0, pB1);
      ldA2<2>(pA0, pA1, wa, wb, 2 * u + 2); ldB2<2>(pB0, pB1, xb0, xb1, 2 * u + 2);
      mm_22<2>(a00, a01, a10, a11, qA0, qA1, qB0, qB1);
      ldA2<2>(qA0, qA1, wa, wb, 2 * u + 3); ldB2<2>(qB0, qB1, xb0, xb1, 2 * u + 3);
    }
    mm_22<2>(a00, a01, a10, a11, pA0, pA1, pB0, pB1);
    mm_22<2>(a00, a01, a10, a11, qA0, qA1, qB0, qB1);
    store_tile<true>(a00, Hc, SHC, 0,  (2 * w) * 32,     b0 + 512 + (2 * w) * 32,     lane);
    store_tile<true>(a01, Hc, SHC, 32, (2 * w) * 32,     b0 + 512 + (2 * w) * 32,     lane);
    store_tile<true>(a10, Hc, SHC, 0,  (2 * w + 1) * 32, b0 + 512 + (2 * w + 1) * 32, lane);
    store_tile<true>(a11, Hc, SHC, 32, (2 * w + 1) * 32, b0 + 512 + (2 * w + 1) * 32, lane);
  }
  __syncthreads();   // b4

  // ================= L1 chunk1: K 512..1023 (weight kt 32..63), 16 batch2, 2-deep =================
  {
    const _Float16* wa = w1a + 32 * 512;
    const _Float16* wb = w1b + 32 * 512;
    half8 sA0[2], sA1[2], sB0[2], sB1[2], tA0[2], tA1[2], tB0[2], tB1[2];
    ldA2<2>(sA0, sA1, wa, wb, 0); ldB2<2>(sB0, sB1, hb0, hb1, 0);
    ldA2<2>(tA0, tA1, wa, wb, 1); ldB2<2>(tB0, tB1, hb0, hb1, 1);
#pragma unroll 1
    for (int u = 0; u < 7; ++u) {
      mm_22<2>(a2_00, a2_01, a2_10, a2_11, sA0, sA1, sB0, sB1);
      ldA2<2>(sA0, sA1, wa, wb, 2 * u + 2); ldB2<2>(sB0, sB1, hb0, hb1, 2 * u + 2);
      mm_22<2>(a2_00, a2_01, a2_10, a2_11, tA0, tA1, tB0, tB1);
      ldA2<2>(tA0, tA1, wa, wb, 2 * u + 3); ldB2<2>(tB0, tB1, hb0, hb1, 2 * u + 3);
    }
    mm_22<2>(a2_00, a2_01, a2_10, a2_11, sA0, sA1, sB0, sB1);
    mm_22<2>(a2_00, a2_01, a2_10, a2_11, tA0, tA1, tB0, tB1);
  }
  __syncthreads();   // b5 (all X/Hc reads complete)

  // ---- H2 stores (overlay X + Hc rows 0..7) ----
  store_tile<true>(a2_00, H2r, S2H, 0,  (2 * w) * 32,     b1 + (2 * w) * 32,     lane);
  store_tile<true>(a2_01, H2r, S2H, 32, (2 * w) * 32,     b1 + (2 * w) * 32,     lane);
  store_tile<true>(a2_10, H2r, S2H, 0,  (2 * w + 1) * 32, b1 + (2 * w + 1) * 32, lane);
  store_tile<true>(a2_11, H2r, S2H, 32, (2 * w + 1) * 32, b1 + (2 * w + 1) * 32, lane);
  __syncthreads();   // b6

  // ================= L2: K=512 -> 256, j2=w, 2mt, 32 kt = 16 batch2, 2-deep =================
  {
    const _Float16* wb2 = W2p + ((size_t)w * 32 * 64 + lane) * 8;
    const _Float16* h2b0 = H2r + (size_t)m31 * S2H + s8;
    const _Float16* h2b1 = h2b0 + 32 * S2H;
    f32x16 a3lo = zero16(), a3hi = zero16();
    half8 sA[2], sB0[2], sB1[2], tA[2], tB0[2], tB1[2];
    ldA1<2>(sA, wb2, 0); ldB2<2>(sB0, sB1, h2b0, h2b1, 0);
    ldA1<2>(tA, wb2, 1); ldB2<2>(tB0, tB1, h2b0, h2b1, 1);
#pragma unroll 1
    for (int u = 0; u < 7; ++u) {
      mm_12<2>(a3lo, a3hi, sA, sB0, sB1);
      ldA1<2>(sA, wb2, 2 * u + 2); ldB2<2>(sB0, sB1, h2b0, h2b1, 2 * u + 2);
      mm_12<2>(a3lo, a3hi, tA, tB0, tB1);
      ldA1<2>(tA, wb2, 2 * u + 3); ldB2<2>(tB0, tB1, h2b0, h2b1, 2 * u + 3);
    }
    mm_12<2>(a3lo, a3hi, sA, sB0, sB1);
    mm_12<2>(a3lo, a3hi, tA, tB0, tB1);
    // H3 region overlaps nothing -> safe to store before barrier
    store_tile<true>(a3lo, H3r, S3, 0,  w * 32, b2 + w * 32, lane);
    store_tile<true>(a3hi, H3r, S3, 32, w * 32, b2 + w * 32, lane);
  }
  __syncthreads();   // b7 (all H2 reads done)

  // ================= L3: K=256 -> 128, j3=w&3, mt=w>>2, 16 kt, batch4 2-deep =================
  {
    const int j3 = w & 3, mts = w >> 2;
    const _Float16* wb3 = W3p + ((size_t)j3 * 16 * 64 + lane) * 8;
    const _Float16* h3b = H3r + (size_t)(mts * 32 + m31) * S3 + s8;
    f32x16 a4 = zero16();
    half8 sA[4], sB[4], tA[4], tB[4];
    ldA1<4>(sA, wb3, 0); ldB1<4>(sB, h3b, 0);
    ldA1<4>(tA, wb3, 1); ldB1<4>(tB, h3b, 1);
    mm_11<4>(a4, sA, sB);
    ldA1<4>(sA, wb3, 2); ldB1<4>(sB, h3b, 2);
    mm_11<4>(a4, tA, tB);
    ldA1<4>(tA, wb3, 3); ldB1<4>(tB, h3b, 3);
    mm_11<4>(a4, sA, sB);
    mm_11<4>(a4, tA, tB);
    store_tile<true>(a4, H4r, S4, mts * 32, j3 * 32, b3 + j3 * 32, lane);
  }
  __syncthreads();   // b8

  // ---- L4: [64][128] @ W4^T -> [64][2] ----
  {
    const int m = tid >> 3;
    const int sub = tid & 7;
    const int j = sub & 1;
    const int q = sub >> 1;
    const _Float16* h4 = H4r + (size_t)m * S4 + q * 32;
    const float* w4 = W4 + j * CC + q * 32;
    float s = 0.f;
#pragma unroll
    for (int cc = 0; cc < 32; ++cc) s += (float)h4[cc] * w4[cc];
    s += __shfl_xor(s, 2);
    s += __shfl_xor(s, 4);
    if (q == 0) preds[(size_t)(m0 + m) * 2 + j] = s + b4[j];
  }
}

// ---------- softmax-combine over the 4 samples ----------
__global__ void jiif_combine(const float* __restrict__ preds, float* __restrict__ out) {
  const int i = blockIdx.x * 256 + threadIdx.x;
  if (i >= BN * NN) return;
  float p0[4], p1[4];
#pragma unroll
  for (int k = 0; k < 4; ++k) {
    p0[k] = preds[((size_t)k * BN * NN + i) * 2 + 0];
    p1[k] = preds[((size_t)k * BN * NN + i) * 2 + 1];
  }
  float mx = fmaxf(fmaxf(p1[0], p1[1]), fmaxf(p1[2], p1[3]));
  float se = 0.f, so = 0.f;
#pragma unroll
  for (int k = 0; k < 4; ++k) {
    float e = expf(p1[k] - mx);
    se += e;
    so += p0[k] * e;
  }
  out[i] = so / se;
}

extern "C" void kernel_launch(void* const* d_in, const int* in_sizes, int n_in,
                              void* d_out, int out_size, void* d_ws, size_t ws_size,
                              hipStream_t stream) {
  const float* feat  = (const float*)d_in[0];
  const float* coord = (const float*)d_in[1];
  const float* hr    = (const float*)d_in[2];
  const float* lr    = (const float*)d_in[3];
  const float* W0 = (const float*)d_in[4];  const float* b0 = (const float*)d_in[5];
  const float* W1 = (const float*)d_in[6];  const float* b1 = (const float*)d_in[7];
  const float* W2 = (const float*)d_in[8];  const float* b2 = (const float*)d_in[9];
  const float* W3 = (const float*)d_in[10]; const float* b3 = (const float*)d_in[11];
  const float* W4 = (const float*)d_in[12]; const float* b4 = (const float*)d_in[13];

  char* ws = (char*)d_ws;
  _Float16* W0p   = (_Float16*)(ws + 0);          // 32*28*512*2  =   917504
  _Float16* W1p   = (_Float16*)(ws + 917504);     // 16*64*512*2  =  1048576
  _Float16* W2p   = (_Float16*)(ws + 1966080);    // 8*32*512*2   =   262144
  _Float16* W3p   = (_Float16*)(ws + 2228224);    // 4*16*512*2   =    65536
  _Float16* featT = (_Float16*)(ws + 2293760);    // 2097152
  _Float16* hrT   = (_Float16*)(ws + 4390912);    // 33554432
  _Float16* lrT   = (_Float16*)(ws + 37945344);   // 2097152
  float* preds    = (float*)(ws + 40042496);      // 1048576 -> total 41091072
  if (ws_size < 41091072) return;

  pack_w<<<224, 256, 0, stream>>>(W0, W0p, 32, 386, 28);
  pack_w<<<256, 256, 0, stream>>>(W1, W1p, 16, 1024, 64);
  pack_w<<<64,  256, 0, stream>>>(W2, W2p, 8, 512, 32);
  pack_w<<<16,  256, 0, stream>>>(W3, W3p, 4, 256, 16);

  transpose_to_hwc<<<dim3(2, 4, 128), dim3(32, 8), 0, stream>>>(feat, featT, CC, FH, FW);
  transpose_to_hwc<<<dim3(8, 4, 512), dim3(32, 8), 0, stream>>>(hr,   hrT,   CC, GH, GW);
  transpose_to_hwc<<<dim3(2, 4, 128), dim3(32, 8), 0, stream>>>(lr,   lrT,   CC, FH, FW);

  (void)hipFuncSetAttribute((const void*)jiif_main,
                            hipFuncAttributeMaxDynamicSharedMemorySize, LDS_ELEMS * 2);
  jiif_main<<<NBLK, 512, LDS_ELEMS * 2, stream>>>(
      coord, featT, hrT, lrT, W0p, W1p, W2p, W3p, b0, b1, b2, b3, W4, b4, preds);

  jiif_combine<<<(BN * NN + 255) / 256, 256, 0, stream>>>(preds, (float*)d_out);
}